// Round 11
// baseline (456.279 us; speedup 1.0000x reference)
//
#include <hip/hip_runtime.h>
#include <hip/hip_bf16.h>
#include <stdint.h>

#define N_NODES 100000
#define NE      250000
#define SDIM    128
#define CDIM    768
#define HS      64
#define HC      192
#define TILE_E  32
#define NBLK    ((NE + TILE_E - 1) / TILE_E)

#define CT2     32                       // edges per chem tile
#define NT2     ((NE + CT2 - 1) / CT2)   // 7813 tiles (last has 16 edges)
#define CBLK2   256                      // persistent chem blocks (1/CU)

typedef __attribute__((ext_vector_type(8))) short bf16x8;
typedef __attribute__((ext_vector_type(4))) float f32x4;

static __device__ __forceinline__ uint16_t f2bf(float f) {
    union { __hip_bfloat16 h; uint16_t u; } cv;
    cv.h = __float2bfloat16(f);
    return cv.u;
}
static __device__ __forceinline__ float bf2f(uint16_t u) {
    union { float f; uint32_t i; } cv; cv.i = ((uint32_t)u) << 16; return cv.f;
}

// ---------------- phase 0: W1c (768x192 f32) -> W1c^T (192x768 bf16) ---------
__global__ void k_convert_w(const float* __restrict__ W1c, uint16_t* __restrict__ W1cT) {
    const int tid = blockIdx.x * 256 + threadIdx.x;
    const int stride = gridDim.x * 256;
    for (int i = tid; i < HC * CDIM; i += stride) {
        const int n = i / CDIM, k = i - n * CDIM;
        W1cT[i] = f2bf(W1c[k * HC + n]);
    }
}

// ------- structural path (exact f32) + valid[] + chem bf16 conversion tail ---
__global__ __launch_bounds__(256, 3) void k_structural(
    const float* __restrict__ z, const int* __restrict__ edge,
    const float* __restrict__ W1s, const float* __restrict__ b1s,
    const float* __restrict__ W2s, const float* __restrict__ b2s,
    const float* __restrict__ smask, const float* __restrict__ alphap,
    float* __restrict__ out, float* __restrict__ valid,
    const float* __restrict__ chem, uint16_t* __restrict__ chem_bf, long conv_n)
{
    __shared__ float Wl[SDIM * HS];
    __shared__ float Pl[TILE_E * 132];

    const int t = threadIdx.x;
    const int e0 = blockIdx.x * TILE_E;

    {
        const float4* src = (const float4*)W1s;
        float4* dst = (float4*)Wl;
        for (int m = t; m < SDIM * HS / 4; m += 256) dst[m] = src[m];
    }
    {
        const int el = t >> 3, p = t & 7;
        const int e = e0 + el;
        if (e < NE) {
            const int s = edge[2 * e], d = edge[2 * e + 1];
            const float* rs = z + (long)s * SDIM;
            const float* rd = z + (long)d * SDIM;
            #pragma unroll
            for (int cc = 0; cc < 2; ++cc) {
                const int c = p + cc * 8;
                float4 s0 = *(const float4*)(rs + c * 8);
                float4 s1 = *(const float4*)(rs + c * 8 + 4);
                float4 d0 = *(const float4*)(rd + c * 8);
                float4 d1 = *(const float4*)(rd + c * 8 + 4);
                float4 r0 = {s0.x * d0.x, s0.y * d0.y, s0.z * d0.z, s0.w * d0.w};
                float4 r1 = {s1.x * d1.x, s1.y * d1.y, s1.z * d1.z, s1.w * d1.w};
                *(float4*)(&Pl[el * 132 + c * 8]) = r0;
                *(float4*)(&Pl[el * 132 + c * 8 + 4]) = r1;
            }
        }
    }
    __syncthreads();

    const int el = t >> 3, p = t & 7;
    float h[8] = {0, 0, 0, 0, 0, 0, 0, 0};
    const float4* Wl4 = (const float4*)Wl;
    #pragma unroll 4
    for (int k = 0; k < SDIM; ++k) {
        const float pv = Pl[el * 132 + k];
        float4 w0 = Wl4[k * 16 + p * 2];
        float4 w1 = Wl4[k * 16 + p * 2 + 1];
        h[0] += pv * w0.x; h[1] += pv * w0.y; h[2] += pv * w0.z; h[3] += pv * w0.w;
        h[4] += pv * w1.x; h[5] += pv * w1.y; h[6] += pv * w1.z; h[7] += pv * w1.w;
    }
    float partial = 0.f;
    #pragma unroll
    for (int j = 0; j < 8; ++j) {
        const int c = p * 8 + j;
        partial += fmaxf(h[j] + b1s[c], 0.f) * W2s[c];
    }
    partial += __shfl_xor(partial, 1);
    partial += __shfl_xor(partial, 2);
    partial += __shfl_xor(partial, 4);
    const int e = e0 + el;
    if (p == 0 && e < NE) {
        out[e] = partial + b2s[0];
        const int s = edge[2 * e], d = edge[2 * e + 1];
        valid[e] = alphap[0] * smask[s] * smask[d];
    }

    // ---- chem f32 -> bf16 conversion tail (grid-stride, streaming) ----
    {
        const long base = ((long)blockIdx.x * 256 + t) * 8;
        const long stride = (long)gridDim.x * 256 * 8;
        for (long i = base; i < conv_n; i += stride) {
            float4 a = *(const float4*)(chem + i);
            float4 b = *(const float4*)(chem + i + 4);
            union { uint16_t u[8]; int4 v; } pk;
            pk.u[0] = f2bf(a.x); pk.u[1] = f2bf(a.y);
            pk.u[2] = f2bf(a.z); pk.u[3] = f2bf(a.w);
            pk.u[4] = f2bf(b.x); pk.u[5] = f2bf(b.y);
            pk.u[6] = f2bf(b.z); pk.u[7] = f2bf(b.w);
            *(int4*)(chem_bf + i) = pk.v;
        }
    }
}

// ---------------- chemistry: v5 = v4 + waves_per_eu(3,3) + T14 + LDS ebuf ----
static __device__ __forceinline__ void cvt_store_bf(uint16_t* Abuf, int el, int ch,
                                                    int4 vs, int4 vd) {
    union { int4 v; uint16_t u[8]; } a, b, r;
    a.v = vs; b.v = vd;
    #pragma unroll
    for (int q = 0; q < 8; ++q) r.u[q] = f2bf(bf2f(a.u[q]) * bf2f(b.u[q]));
    const int byte = el * 1536 + ((ch * 16) ^ ((el & 7) << 4));
    *(int4*)((char*)Abuf + byte) = r.v;
}
static __device__ __forceinline__ void zero_store(uint16_t* Abuf, int el, int ch) {
    const int byte = el * 1536 + ((ch * 16) ^ ((el & 7) << 4));
    int4 z = {0, 0, 0, 0};
    *(int4*)((char*)Abuf + byte) = z;
}
static __device__ __forceinline__ void stage_f32(uint16_t* Abuf, int el, int ch,
                                                 const float* rs, const float* rd) {
    float4 a0 = *(const float4*)(rs + ch * 8);
    float4 a1 = *(const float4*)(rs + ch * 8 + 4);
    float4 b0 = *(const float4*)(rd + ch * 8);
    float4 b1 = *(const float4*)(rd + ch * 8 + 4);
    union { int4 v; uint16_t u[8]; } r;
    r.u[0] = f2bf(a0.x * b0.x); r.u[1] = f2bf(a0.y * b0.y);
    r.u[2] = f2bf(a0.z * b0.z); r.u[3] = f2bf(a0.w * b0.w);
    r.u[4] = f2bf(a1.x * b1.x); r.u[5] = f2bf(a1.y * b1.y);
    r.u[6] = f2bf(a1.z * b1.z); r.u[7] = f2bf(a1.w * b1.w);
    const int byte = el * 1536 + ((ch * 16) ^ ((el & 7) << 4));
    *(int4*)((char*)Abuf + byte) = r.v;
}

template<bool BF16TAB>
__global__ __attribute__((amdgpu_waves_per_eu(3, 3))) __launch_bounds__(768)
void k_chem_v5(
    const void* __restrict__ chemv, const int* __restrict__ edge,
    const uint16_t* __restrict__ W1cT, const float* __restrict__ b1c,
    const float* __restrict__ W2c, const float* __restrict__ b2c,
    const float* __restrict__ valid, float* __restrict__ out)
{
    __shared__ uint16_t A[2][CT2 * CDIM];   // 2 x 48KB, XOR-swizzled rows
    __shared__ float xchg[6][64][20];       // 30KB K-half exchange
    __shared__ float part[2][CT2][8];       // per-edge partials, 6 cg + pad
    __shared__ int   ebuf[2][2 * CT2];      // edge-index ring, 2 tiles ahead

    const int t = threadIdx.x;              // 768 threads = 12 waves
    const int w = t >> 6, lane = t & 63, lr = lane & 15, lg = lane >> 4;
    const int cg = w >> 1, kh = w & 1;      // 6 col-groups x 2 K-halves
    const int b = blockIdx.x;

    const int t0 = b * 30 + (b < 133 ? b : 133);
    const int t1 = t0 + 30 + (b < 133 ? 1 : 0);

    const uint16_t* chemB = (const uint16_t*)chemv;
    const float*    chemF = (const float*)chemv;

    // ---- B slice (once): cols [cg*32 + ct*16 + lr], K-half kh ----
    bf16x8 Breg[24];
    #pragma unroll
    for (int ct = 0; ct < 2; ++ct) {
        const uint16_t* Bp = W1cT + (long)(cg * 32 + ct * 16 + lr) * CDIM + kh * 384 + lg * 8;
        #pragma unroll
        for (int kc = 0; kc < 12; ++kc)
            Breg[ct * 12 + kc] = *(const bf16x8*)(Bp + kc * 32);
    }
    float b1v[2], w2v[2];
    #pragma unroll
    for (int ct = 0; ct < 2; ++ct) {
        b1v[ct] = b1c[cg * 32 + ct * 16 + lr];
        w2v[ct] = W2c[cg * 32 + ct * 16 + lr];
    }
    const float b2 = b2c[0];

    // staging: 3072 slots, 4/thread
    const int elb = t / 96;                 // 0..7
    const int ch  = t % 96;

    // ---- prologue: stage tile t0 synchronously ----
    #pragma unroll
    for (int q = 0; q < 4; ++q) {
        const int el = elb + 8 * q;
        const int e  = t0 * CT2 + el;
        const bool ok = (e < NE);
        const int ee = ok ? e : 0;
        const int si = edge[2 * ee], di = edge[2 * ee + 1];
        if constexpr (BF16TAB) {
            int4 vs = *(const int4*)(chemB + (long)si * CDIM + ch * 8);
            int4 vd = *(const int4*)(chemB + (long)di * CDIM + ch * 8);
            if (ok) cvt_store_bf(A[0], el, ch, vs, vd);
            else    zero_store(A[0], el, ch);
        } else {
            if (ok) stage_f32(A[0], el, ch, chemF + (long)si * CDIM, chemF + (long)di * CDIM);
            else    zero_store(A[0], el, ch);
        }
    }
    // prologue: edge indices for tile t0+1 into ebuf[(t0+1)&1]
    if (t < CT2) {
        const int e = (t0 + 1) * CT2 + t;
        const int ee = (e < NE) ? e : 0;
        int2 p2 = *(const int2*)(edge + 2 * ee);
        *(int2*)&ebuf[(t0 + 1) & 1][2 * t] = p2;
    }
    float vld_cur = 0.f, vld_next = 0.f;
    if (t < CT2) {
        const int e = t0 * CT2 + t;
        vld_next = (e < NE) ? valid[e] : 0.f;
    }
    __syncthreads();

    const int swz = (lr & 7) << 4;
    const int rb0 = lr * 1536;
    const int rb1 = rb0 + 16 * 1536;

    for (int ti = t0; ti < t1; ++ti) {
        const int it = ti - t0, cur = it & 1;
        const bool pf  = (ti + 1 < t1);
        const bool pf2 = (ti + 2 < t1);

        // ---- (1) T14 issue: gathers for tile ti+1, held in regs across compute
        int4 vs0, vd0, vs1, vd1, vs2, vd2, vs3, vd3;
        if (BF16TAB && pf) {
            const int par = (ti + 1) & 1;
            int2 e0p = *(const int2*)&ebuf[par][2 * elb];
            int2 e1p = *(const int2*)&ebuf[par][2 * (elb + 8)];
            int2 e2p = *(const int2*)&ebuf[par][2 * (elb + 16)];
            int2 e3p = *(const int2*)&ebuf[par][2 * (elb + 24)];
            vs0 = *(const int4*)(chemB + (long)e0p.x * CDIM + ch * 8);
            vd0 = *(const int4*)(chemB + (long)e0p.y * CDIM + ch * 8);
            vs1 = *(const int4*)(chemB + (long)e1p.x * CDIM + ch * 8);
            vd1 = *(const int4*)(chemB + (long)e1p.y * CDIM + ch * 8);
            vs2 = *(const int4*)(chemB + (long)e2p.x * CDIM + ch * 8);
            vd2 = *(const int4*)(chemB + (long)e2p.y * CDIM + ch * 8);
            vs3 = *(const int4*)(chemB + (long)e3p.x * CDIM + ch * 8);
            vd3 = *(const int4*)(chemB + (long)e3p.y * CDIM + ch * 8);
        }
        // ---- (2) stage edge indices for tile ti+2 into ebuf[ti&1]
        if (pf2 && t < CT2) {
            const int e = (ti + 2) * CT2 + t;
            const int ee = (e < NE) ? e : 0;
            int2 p2 = *(const int2*)(edge + 2 * ee);
            *(int2*)&ebuf[ti & 1][2 * t] = p2;
        }

        // ---- (3) epilogue tile ti-1 (fire-and-forget atomic)
        if (ti > t0 && t < CT2) {
            const int e = (ti - 1) * CT2 + t;
            if (e < NE) {
                float s_ = 0.f;
                #pragma unroll
                for (int c6 = 0; c6 < 6; ++c6) s_ += part[cur ^ 1][t][c6];
                atomicAdd(&out[e], vld_cur * (s_ + b2));
            }
        }
        if (t < CT2) {
            vld_cur = vld_next;
            if (pf) {
                const int e = (ti + 1) * CT2 + t;
                vld_next = (e < NE) ? valid[e] : 0.f;
            }
        }

        // ---- (4) MFMA: 12 K-slices x 2 rowgrp x 2 coltile
        f32x4 acc00 = {0,0,0,0}, acc01 = {0,0,0,0}, acc10 = {0,0,0,0}, acc11 = {0,0,0,0};
        {
            const char* Ab = (const char*)A[cur];
            #pragma unroll
            for (int kc = 0; kc < 12; ++kc) {
                const int off = ((kh * 12 + kc) * 64 + lg * 16) ^ swz;
                bf16x8 a0 = *(const bf16x8*)(Ab + rb0 + off);
                bf16x8 a1 = *(const bf16x8*)(Ab + rb1 + off);
                acc00 = __builtin_amdgcn_mfma_f32_16x16x32_bf16(a0, Breg[kc],      acc00, 0, 0, 0);
                acc10 = __builtin_amdgcn_mfma_f32_16x16x32_bf16(a1, Breg[kc],      acc10, 0, 0, 0);
                acc01 = __builtin_amdgcn_mfma_f32_16x16x32_bf16(a0, Breg[12 + kc], acc01, 0, 0, 0);
                acc11 = __builtin_amdgcn_mfma_f32_16x16x32_bf16(a1, Breg[12 + kc], acc11, 0, 0, 0);
            }
        }

        // ---- (5) K-half exchange: kh=1 writes, kh=0 combines + reduces
        if (kh == 1) {
            float* xp = xchg[cg][lane];
            *(float4*)(xp +  0) = (float4){acc00[0], acc00[1], acc00[2], acc00[3]};
            *(float4*)(xp +  4) = (float4){acc01[0], acc01[1], acc01[2], acc01[3]};
            *(float4*)(xp +  8) = (float4){acc10[0], acc10[1], acc10[2], acc10[3]};
            *(float4*)(xp + 12) = (float4){acc11[0], acc11[1], acc11[2], acc11[3]};
        }
        __syncthreads();
        if (kh == 0) {
            const float* xp = xchg[cg][lane];
            float4 x0 = *(const float4*)(xp + 0);
            float4 x1 = *(const float4*)(xp + 4);
            float4 x2 = *(const float4*)(xp + 8);
            float4 x3 = *(const float4*)(xp + 12);
            acc00[0] += x0.x; acc00[1] += x0.y; acc00[2] += x0.z; acc00[3] += x0.w;
            acc01[0] += x1.x; acc01[1] += x1.y; acc01[2] += x1.z; acc01[3] += x1.w;
            acc10[0] += x2.x; acc10[1] += x2.y; acc10[2] += x2.z; acc10[3] += x2.w;
            acc11[0] += x3.x; acc11[1] += x3.y; acc11[2] += x3.z; acc11[3] += x3.w;
            #pragma unroll
            for (int r = 0; r < 4; ++r) {
                float p0 = fmaxf(acc00[r] + b1v[0], 0.f) * w2v[0]
                         + fmaxf(acc01[r] + b1v[1], 0.f) * w2v[1];
                float p1 = fmaxf(acc10[r] + b1v[0], 0.f) * w2v[0]
                         + fmaxf(acc11[r] + b1v[1], 0.f) * w2v[1];
                #pragma unroll
                for (int m = 1; m <= 8; m <<= 1) {
                    p0 += __shfl_xor(p0, m);
                    p1 += __shfl_xor(p1, m);
                }
                if (lr == 0) {
                    part[cur][lg * 4 + r][cg]      = p0;
                    part[cur][16 + lg * 4 + r][cg] = p1;
                }
            }
        }

        // ---- (6) T14 consume: cvt + ds_write staged tile ti+1
        if (pf) {
            uint16_t* dst = A[cur ^ 1];
            const int ebase = (ti + 1) * CT2;
            if constexpr (BF16TAB) {
                if (ebase + elb < NE)      cvt_store_bf(dst, elb,      ch, vs0, vd0);
                else                       zero_store(dst, elb, ch);
                if (ebase + elb + 8 < NE)  cvt_store_bf(dst, elb + 8,  ch, vs1, vd1);
                else                       zero_store(dst, elb + 8, ch);
                if (ebase + elb + 16 < NE) cvt_store_bf(dst, elb + 16, ch, vs2, vd2);
                else                       zero_store(dst, elb + 16, ch);
                if (ebase + elb + 24 < NE) cvt_store_bf(dst, elb + 24, ch, vs3, vd3);
                else                       zero_store(dst, elb + 24, ch);
            } else {
                const int par = (ti + 1) & 1;
                #pragma unroll
                for (int q = 0; q < 4; ++q) {
                    const int el = elb + 8 * q;
                    if (ebase + el < NE) {
                        int2 p2 = *(const int2*)&ebuf[par][2 * el];
                        stage_f32(dst, el, ch, chemF + (long)p2.x * CDIM,
                                  chemF + (long)p2.y * CDIM);
                    } else zero_store(dst, el, ch);
                }
            }
        }
        __syncthreads();
    }

    // final tile epilogue
    if (t < CT2) {
        const int e = (t1 - 1) * CT2 + t;
        if (e < NE) {
            const int cur = (t1 - 1 - t0) & 1;
            float s_ = 0.f;
            #pragma unroll
            for (int c6 = 0; c6 < 6; ++c6) s_ += part[cur][t][c6];
            atomicAdd(&out[e], vld_cur * (s_ + b2));
        }
    }
}

extern "C" void kernel_launch(void* const* d_in, const int* in_sizes, int n_in,
                              void* d_out, int out_size, void* d_ws, size_t ws_size,
                              hipStream_t stream)
{
    const float* z     = (const float*)d_in[0];
    const float* chem  = (const float*)d_in[1];
    const int*   edge  = (const int*)d_in[2];
    const float* smask = (const float*)d_in[3];
    const float* W1s   = (const float*)d_in[4];
    const float* b1s   = (const float*)d_in[5];
    const float* W2s   = (const float*)d_in[6];
    const float* b2s   = (const float*)d_in[7];
    const float* W1c   = (const float*)d_in[8];
    const float* b1c   = (const float*)d_in[9];
    const float* W2c   = (const float*)d_in[10];
    const float* b2c   = (const float*)d_in[11];
    const float* alpha = (const float*)d_in[12];
    float* out = (float*)d_out;

    // ws layout: W1cT (294912 B) | chemBf (153.6 MB, if fits) | valid (1 MB)
    uint16_t* W1cT   = (uint16_t*)d_ws;
    uint16_t* chemBf = (uint16_t*)d_ws + (size_t)HC * CDIM;
    const size_t bfBytes = (size_t)N_NODES * CDIM * 2;
    const size_t needBf  = (size_t)HC * CDIM * 2 + bfBytes + (size_t)NE * 4;
    const bool useBf = ws_size >= needBf;
    float* valid = useBf
        ? (float*)((char*)d_ws + (size_t)HC * CDIM * 2 + bfBytes)
        : (float*)((char*)d_ws + (size_t)HC * CDIM * 2);
    const long conv_n = useBf ? (long)N_NODES * CDIM : 0;

    k_convert_w<<<dim3(64), dim3(256), 0, stream>>>(W1c, W1cT);

    k_structural<<<dim3(NBLK), dim3(256), 0, stream>>>(
        z, edge, W1s, b1s, W2s, b2s, smask, alpha, out, valid, chem, chemBf, conv_n);

    if (useBf)
        k_chem_v5<true><<<dim3(CBLK2), dim3(768), 0, stream>>>(
            (const void*)chemBf, edge, W1cT, b1c, W2c, b2c, valid, out);
    else
        k_chem_v5<false><<<dim3(CBLK2), dim3(768), 0, stream>>>(
            (const void*)chem, edge, W1cT, b1c, W2c, b2c, valid, out);
}

// Round 12
// 325.653 us; speedup vs baseline: 1.4011x; 1.4011x over previous
//
#include <hip/hip_runtime.h>
#include <hip/hip_bf16.h>
#include <stdint.h>

#define N_NODES 100000
#define NE      250000
#define SDIM    128
#define CDIM    768
#define HS      64
#define HC      192
#define TILE_E  32
#define NBLK    ((NE + TILE_E - 1) / TILE_E)

#define CT2     32                       // edges per chem tile
#define NT2     ((NE + CT2 - 1) / CT2)   // 7813 tiles (last has 16 edges)
#define CBLK2   256                      // persistent chem blocks (1/CU)

typedef __attribute__((ext_vector_type(8))) short bf16x8;
typedef __attribute__((ext_vector_type(4))) float f32x4;

static __device__ __forceinline__ uint16_t f2bf(float f) {
    union { __hip_bfloat16 h; uint16_t u; } cv;
    cv.h = __float2bfloat16(f);
    return cv.u;
}
static __device__ __forceinline__ float bf2f(uint16_t u) {
    union { float f; uint32_t i; } cv; cv.i = ((uint32_t)u) << 16; return cv.f;
}

// ---------------- phase 0: W1c (768x192 f32) -> W1c^T (192x768 bf16) ---------
__global__ void k_convert_w(const float* __restrict__ W1c, uint16_t* __restrict__ W1cT) {
    const int tid = blockIdx.x * 256 + threadIdx.x;
    const int stride = gridDim.x * 256;
    for (int i = tid; i < HC * CDIM; i += stride) {
        const int n = i / CDIM, k = i - n * CDIM;
        W1cT[i] = f2bf(W1c[k * HC + n]);
    }
}

// ------- structural path (exact f32) + valid[] + chem bf16 conversion tail ---
__global__ __launch_bounds__(256, 3) void k_structural(
    const float* __restrict__ z, const int* __restrict__ edge,
    const float* __restrict__ W1s, const float* __restrict__ b1s,
    const float* __restrict__ W2s, const float* __restrict__ b2s,
    const float* __restrict__ smask, const float* __restrict__ alphap,
    float* __restrict__ out, float* __restrict__ valid,
    const float* __restrict__ chem, uint16_t* __restrict__ chem_bf, long conv_n)
{
    __shared__ float Wl[SDIM * HS];
    __shared__ float Pl[TILE_E * 132];

    const int t = threadIdx.x;
    const int e0 = blockIdx.x * TILE_E;

    {
        const float4* src = (const float4*)W1s;
        float4* dst = (float4*)Wl;
        for (int m = t; m < SDIM * HS / 4; m += 256) dst[m] = src[m];
    }
    {
        const int el = t >> 3, p = t & 7;
        const int e = e0 + el;
        if (e < NE) {
            const int s = edge[2 * e], d = edge[2 * e + 1];
            const float* rs = z + (long)s * SDIM;
            const float* rd = z + (long)d * SDIM;
            #pragma unroll
            for (int cc = 0; cc < 2; ++cc) {
                const int c = p + cc * 8;
                float4 s0 = *(const float4*)(rs + c * 8);
                float4 s1 = *(const float4*)(rs + c * 8 + 4);
                float4 d0 = *(const float4*)(rd + c * 8);
                float4 d1 = *(const float4*)(rd + c * 8 + 4);
                float4 r0 = {s0.x * d0.x, s0.y * d0.y, s0.z * d0.z, s0.w * d0.w};
                float4 r1 = {s1.x * d1.x, s1.y * d1.y, s1.z * d1.z, s1.w * d1.w};
                *(float4*)(&Pl[el * 132 + c * 8]) = r0;
                *(float4*)(&Pl[el * 132 + c * 8 + 4]) = r1;
            }
        }
    }
    __syncthreads();

    const int el = t >> 3, p = t & 7;
    float h[8] = {0, 0, 0, 0, 0, 0, 0, 0};
    const float4* Wl4 = (const float4*)Wl;
    #pragma unroll 4
    for (int k = 0; k < SDIM; ++k) {
        const float pv = Pl[el * 132 + k];
        float4 w0 = Wl4[k * 16 + p * 2];
        float4 w1 = Wl4[k * 16 + p * 2 + 1];
        h[0] += pv * w0.x; h[1] += pv * w0.y; h[2] += pv * w0.z; h[3] += pv * w0.w;
        h[4] += pv * w1.x; h[5] += pv * w1.y; h[6] += pv * w1.z; h[7] += pv * w1.w;
    }
    float partial = 0.f;
    #pragma unroll
    for (int j = 0; j < 8; ++j) {
        const int c = p * 8 + j;
        partial += fmaxf(h[j] + b1s[c], 0.f) * W2s[c];
    }
    partial += __shfl_xor(partial, 1);
    partial += __shfl_xor(partial, 2);
    partial += __shfl_xor(partial, 4);
    const int e = e0 + el;
    if (p == 0 && e < NE) {
        out[e] = partial + b2s[0];
        const int s = edge[2 * e], d = edge[2 * e + 1];
        valid[e] = alphap[0] * smask[s] * smask[d];
    }

    // ---- chem f32 -> bf16 conversion tail (grid-stride, streaming) ----
    {
        const long base = ((long)blockIdx.x * 256 + t) * 8;
        const long stride = (long)gridDim.x * 256 * 8;
        for (long i = base; i < conv_n; i += stride) {
            float4 a = *(const float4*)(chem + i);
            float4 b = *(const float4*)(chem + i + 4);
            union { uint16_t u[8]; int4 v; } pk;
            pk.u[0] = f2bf(a.x); pk.u[1] = f2bf(a.y);
            pk.u[2] = f2bf(a.z); pk.u[3] = f2bf(a.w);
            pk.u[4] = f2bf(b.x); pk.u[5] = f2bf(b.y);
            pk.u[6] = f2bf(b.z); pk.u[7] = f2bf(b.w);
            *(int4*)(chem_bf + i) = pk.v;
        }
    }
}

// ---------------- chemistry: v6 = v4 + forced-resident Breg + LDS ebuf -------
static __device__ __forceinline__ void cvt_store_bf(uint16_t* Abuf, int el, int ch,
                                                    int4 vs, int4 vd) {
    union { int4 v; uint16_t u[8]; } a, b, r;
    a.v = vs; b.v = vd;
    #pragma unroll
    for (int q = 0; q < 8; ++q) r.u[q] = f2bf(bf2f(a.u[q]) * bf2f(b.u[q]));
    const int byte = el * 1536 + ((ch * 16) ^ ((el & 7) << 4));
    *(int4*)((char*)Abuf + byte) = r.v;
}
static __device__ __forceinline__ void zero_store(uint16_t* Abuf, int el, int ch) {
    const int byte = el * 1536 + ((ch * 16) ^ ((el & 7) << 4));
    int4 z = {0, 0, 0, 0};
    *(int4*)((char*)Abuf + byte) = z;
}
static __device__ __forceinline__ void stage_f32(uint16_t* Abuf, int el, int ch,
                                                 const float* rs, const float* rd) {
    float4 a0 = *(const float4*)(rs + ch * 8);
    float4 a1 = *(const float4*)(rs + ch * 8 + 4);
    float4 b0 = *(const float4*)(rd + ch * 8);
    float4 b1 = *(const float4*)(rd + ch * 8 + 4);
    union { int4 v; uint16_t u[8]; } r;
    r.u[0] = f2bf(a0.x * b0.x); r.u[1] = f2bf(a0.y * b0.y);
    r.u[2] = f2bf(a0.z * b0.z); r.u[3] = f2bf(a0.w * b0.w);
    r.u[4] = f2bf(a1.x * b1.x); r.u[5] = f2bf(a1.y * b1.y);
    r.u[6] = f2bf(a1.z * b1.z); r.u[7] = f2bf(a1.w * b1.w);
    const int byte = el * 1536 + ((ch * 16) ^ ((el & 7) << 4));
    *(int4*)((char*)Abuf + byte) = r.v;
}

template<bool BF16TAB>
__global__ __launch_bounds__(768, 3) void k_chem_v6(
    const void* __restrict__ chemv, const int* __restrict__ edge,
    const uint16_t* __restrict__ W1cT, const float* __restrict__ b1c,
    const float* __restrict__ W2c, const float* __restrict__ b2c,
    const float* __restrict__ valid, float* __restrict__ out)
{
    __shared__ uint16_t A[2][CT2 * CDIM];   // 2 x 48KB, XOR-swizzled rows
    __shared__ float xchg[6][64][20];       // 30KB K-half exchange
    __shared__ float part[2][CT2][8];       // per-edge partials, 6 cg + pad
    __shared__ int   ebuf[2][2 * CT2];      // edge-index ring (2 tiles ahead)

    const int t = threadIdx.x;              // 768 threads = 12 waves
    const int w = t >> 6, lane = t & 63, lr = lane & 15, lg = lane >> 4;
    const int cg = w >> 1, kh = w & 1;      // 6 col-groups x 2 K-halves
    const int b = blockIdx.x;

    const int t0 = b * 30 + (b < 133 ? b : 133);
    const int t1 = t0 + 30 + (b < 133 ? 1 : 0);

    const uint16_t* chemB = (const uint16_t*)chemv;
    const float*    chemF = (const float*)chemv;

    // ---- B slice (once): cols [cg*32 + ct*16 + lr], K-half kh ----
    bf16x8 Breg[24];
    #pragma unroll
    for (int ct = 0; ct < 2; ++ct) {
        const uint16_t* Bp = W1cT + (long)(cg * 32 + ct * 16 + lr) * CDIM + kh * 384 + lg * 8;
        #pragma unroll
        for (int kc = 0; kc < 12; ++kc)
            Breg[ct * 12 + kc] = *(const bf16x8*)(Bp + kc * 32);
    }
    // FORCE materialization: opaque asm makes remat illegal -> B stays in VGPRs
    #pragma unroll
    for (int i = 0; i < 24; ++i) asm volatile("" : "+v"(Breg[i]));

    float b1v[2], w2v[2];
    #pragma unroll
    for (int ct = 0; ct < 2; ++ct) {
        b1v[ct] = b1c[cg * 32 + ct * 16 + lr];
        w2v[ct] = W2c[cg * 32 + ct * 16 + lr];
    }
    const float b2 = b2c[0];

    // staging: 3072 slots, 4/thread
    const int elb = t / 96;                 // 0..7
    const int ch  = t % 96;

    // ---- prologue: stage tile t0 synchronously ----
    #pragma unroll
    for (int q = 0; q < 4; ++q) {
        const int el = elb + 8 * q;
        const int e  = t0 * CT2 + el;
        const bool ok = (e < NE);
        const int ee = ok ? e : 0;
        const int si = edge[2 * ee], di = edge[2 * ee + 1];
        if constexpr (BF16TAB) {
            int4 vs = *(const int4*)(chemB + (long)si * CDIM + ch * 8);
            int4 vd = *(const int4*)(chemB + (long)di * CDIM + ch * 8);
            if (ok) cvt_store_bf(A[0], el, ch, vs, vd);
            else    zero_store(A[0], el, ch);
        } else {
            if (ok) stage_f32(A[0], el, ch, chemF + (long)si * CDIM, chemF + (long)di * CDIM);
            else    zero_store(A[0], el, ch);
        }
    }
    // prologue: edge indices for tile t0+1 into ebuf[(t0+1)&1]
    if (t < CT2) {
        const int e = (t0 + 1) * CT2 + t;
        const int ee = (e < NE) ? e : 0;
        int2 p2 = *(const int2*)(edge + 2 * ee);
        *(int2*)&ebuf[(t0 + 1) & 1][2 * t] = p2;
    }
    float vld_cur = 0.f, vld_next = 0.f;
    if (t < CT2) {
        const int e = t0 * CT2 + t;
        vld_next = (e < NE) ? valid[e] : 0.f;
    }
    __syncthreads();

    const int swz = (lr & 7) << 4;
    const int rb0 = lr * 1536;
    const int rb1 = rb0 + 16 * 1536;

    for (int ti = t0; ti < t1; ++ti) {
        const int it = ti - t0, cur = it & 1;
        const bool pf  = (ti + 1 < t1);
        const bool pf2 = (ti + 2 < t1);

        // ---- (1) stage tile ti+1 direct (2 batches; indices from ebuf) ----
        if (pf) {
            uint16_t* dst = A[cur ^ 1];
            const int ebase = (ti + 1) * CT2;
            const int par = (ti + 1) & 1;
            int2 e0p = *(const int2*)&ebuf[par][2 * elb];
            int2 e1p = *(const int2*)&ebuf[par][2 * (elb + 8)];
            int2 e2p = *(const int2*)&ebuf[par][2 * (elb + 16)];
            int2 e3p = *(const int2*)&ebuf[par][2 * (elb + 24)];
            if constexpr (BF16TAB) {
                {
                    int4 vs0 = *(const int4*)(chemB + (long)e0p.x * CDIM + ch * 8);
                    int4 vd0 = *(const int4*)(chemB + (long)e0p.y * CDIM + ch * 8);
                    int4 vs1 = *(const int4*)(chemB + (long)e1p.x * CDIM + ch * 8);
                    int4 vd1 = *(const int4*)(chemB + (long)e1p.y * CDIM + ch * 8);
                    if (ebase + elb < NE)     cvt_store_bf(dst, elb,     ch, vs0, vd0);
                    else                      zero_store(dst, elb, ch);
                    if (ebase + elb + 8 < NE) cvt_store_bf(dst, elb + 8, ch, vs1, vd1);
                    else                      zero_store(dst, elb + 8, ch);
                }
                {
                    int4 vs2 = *(const int4*)(chemB + (long)e2p.x * CDIM + ch * 8);
                    int4 vd2 = *(const int4*)(chemB + (long)e2p.y * CDIM + ch * 8);
                    int4 vs3 = *(const int4*)(chemB + (long)e3p.x * CDIM + ch * 8);
                    int4 vd3 = *(const int4*)(chemB + (long)e3p.y * CDIM + ch * 8);
                    if (ebase + elb + 16 < NE) cvt_store_bf(dst, elb + 16, ch, vs2, vd2);
                    else                       zero_store(dst, elb + 16, ch);
                    if (ebase + elb + 24 < NE) cvt_store_bf(dst, elb + 24, ch, vs3, vd3);
                    else                       zero_store(dst, elb + 24, ch);
                }
            } else {
                #pragma unroll
                for (int q = 0; q < 4; ++q) {
                    const int el = elb + 8 * q;
                    int2 ep = (q == 0) ? e0p : (q == 1) ? e1p : (q == 2) ? e2p : e3p;
                    if (ebase + el < NE)
                        stage_f32(dst, el, ch, chemF + (long)ep.x * CDIM,
                                  chemF + (long)ep.y * CDIM);
                    else zero_store(dst, el, ch);
                }
            }
        }
        // ---- (2) stage edge indices for tile ti+2 into ebuf[ti&1] ----
        if (pf2 && t < CT2) {
            const int e = (ti + 2) * CT2 + t;
            const int ee = (e < NE) ? e : 0;
            int2 p2 = *(const int2*)(edge + 2 * ee);
            *(int2*)&ebuf[ti & 1][2 * t] = p2;
        }

        // ---- (3) epilogue tile ti-1 (fire-and-forget atomic) ----
        if (ti > t0 && t < CT2) {
            const int e = (ti - 1) * CT2 + t;
            if (e < NE) {
                float s_ = 0.f;
                #pragma unroll
                for (int c6 = 0; c6 < 6; ++c6) s_ += part[cur ^ 1][t][c6];
                atomicAdd(&out[e], vld_cur * (s_ + b2));
            }
        }
        if (t < CT2) {
            vld_cur = vld_next;
            if (pf) {
                const int e = (ti + 1) * CT2 + t;
                vld_next = (e < NE) ? valid[e] : 0.f;
            }
        }

        // ---- (4) MFMA: 12 K-slices x 2 rowgrp x 2 coltile ----
        f32x4 acc00 = {0,0,0,0}, acc01 = {0,0,0,0}, acc10 = {0,0,0,0}, acc11 = {0,0,0,0};
        {
            const char* Ab = (const char*)A[cur];
            #pragma unroll
            for (int kc = 0; kc < 12; ++kc) {
                const int off = ((kh * 12 + kc) * 64 + lg * 16) ^ swz;
                bf16x8 a0 = *(const bf16x8*)(Ab + rb0 + off);
                bf16x8 a1 = *(const bf16x8*)(Ab + rb1 + off);
                acc00 = __builtin_amdgcn_mfma_f32_16x16x32_bf16(a0, Breg[kc],      acc00, 0, 0, 0);
                acc10 = __builtin_amdgcn_mfma_f32_16x16x32_bf16(a1, Breg[kc],      acc10, 0, 0, 0);
                acc01 = __builtin_amdgcn_mfma_f32_16x16x32_bf16(a0, Breg[12 + kc], acc01, 0, 0, 0);
                acc11 = __builtin_amdgcn_mfma_f32_16x16x32_bf16(a1, Breg[12 + kc], acc11, 0, 0, 0);
            }
        }

        // ---- (5) K-half exchange: kh=1 writes, kh=0 combines + reduces ----
        if (kh == 1) {
            float* xp = xchg[cg][lane];
            *(float4*)(xp +  0) = (float4){acc00[0], acc00[1], acc00[2], acc00[3]};
            *(float4*)(xp +  4) = (float4){acc01[0], acc01[1], acc01[2], acc01[3]};
            *(float4*)(xp +  8) = (float4){acc10[0], acc10[1], acc10[2], acc10[3]};
            *(float4*)(xp + 12) = (float4){acc11[0], acc11[1], acc11[2], acc11[3]};
        }
        __syncthreads();
        if (kh == 0) {
            const float* xp = xchg[cg][lane];
            float4 x0 = *(const float4*)(xp + 0);
            float4 x1 = *(const float4*)(xp + 4);
            float4 x2 = *(const float4*)(xp + 8);
            float4 x3 = *(const float4*)(xp + 12);
            acc00[0] += x0.x; acc00[1] += x0.y; acc00[2] += x0.z; acc00[3] += x0.w;
            acc01[0] += x1.x; acc01[1] += x1.y; acc01[2] += x1.z; acc01[3] += x1.w;
            acc10[0] += x2.x; acc10[1] += x2.y; acc10[2] += x2.z; acc10[3] += x2.w;
            acc11[0] += x3.x; acc11[1] += x3.y; acc11[2] += x3.z; acc11[3] += x3.w;
            #pragma unroll
            for (int r = 0; r < 4; ++r) {
                float p0 = fmaxf(acc00[r] + b1v[0], 0.f) * w2v[0]
                         + fmaxf(acc01[r] + b1v[1], 0.f) * w2v[1];
                float p1 = fmaxf(acc10[r] + b1v[0], 0.f) * w2v[0]
                         + fmaxf(acc11[r] + b1v[1], 0.f) * w2v[1];
                #pragma unroll
                for (int m = 1; m <= 8; m <<= 1) {
                    p0 += __shfl_xor(p0, m);
                    p1 += __shfl_xor(p1, m);
                }
                if (lr == 0) {
                    part[cur][lg * 4 + r][cg]      = p0;
                    part[cur][16 + lg * 4 + r][cg] = p1;
                }
            }
        }
        __syncthreads();
    }

    // final tile epilogue
    if (t < CT2) {
        const int e = (t1 - 1) * CT2 + t;
        if (e < NE) {
            const int cur = (t1 - 1 - t0) & 1;
            float s_ = 0.f;
            #pragma unroll
            for (int c6 = 0; c6 < 6; ++c6) s_ += part[cur][t][c6];
            atomicAdd(&out[e], vld_cur * (s_ + b2));
        }
    }
}

extern "C" void kernel_launch(void* const* d_in, const int* in_sizes, int n_in,
                              void* d_out, int out_size, void* d_ws, size_t ws_size,
                              hipStream_t stream)
{
    const float* z     = (const float*)d_in[0];
    const float* chem  = (const float*)d_in[1];
    const int*   edge  = (const int*)d_in[2];
    const float* smask = (const float*)d_in[3];
    const float* W1s   = (const float*)d_in[4];
    const float* b1s   = (const float*)d_in[5];
    const float* W2s   = (const float*)d_in[6];
    const float* b2s   = (const float*)d_in[7];
    const float* W1c   = (const float*)d_in[8];
    const float* b1c   = (const float*)d_in[9];
    const float* W2c   = (const float*)d_in[10];
    const float* b2c   = (const float*)d_in[11];
    const float* alpha = (const float*)d_in[12];
    float* out = (float*)d_out;

    // ws layout: W1cT (294912 B) | chemBf (153.6 MB, if fits) | valid (1 MB)
    uint16_t* W1cT   = (uint16_t*)d_ws;
    uint16_t* chemBf = (uint16_t*)d_ws + (size_t)HC * CDIM;
    const size_t bfBytes = (size_t)N_NODES * CDIM * 2;
    const size_t needBf  = (size_t)HC * CDIM * 2 + bfBytes + (size_t)NE * 4;
    const bool useBf = ws_size >= needBf;
    float* valid = useBf
        ? (float*)((char*)d_ws + (size_t)HC * CDIM * 2 + bfBytes)
        : (float*)((char*)d_ws + (size_t)HC * CDIM * 2);
    const long conv_n = useBf ? (long)N_NODES * CDIM : 0;

    k_convert_w<<<dim3(64), dim3(256), 0, stream>>>(W1c, W1cT);

    k_structural<<<dim3(NBLK), dim3(256), 0, stream>>>(
        z, edge, W1s, b1s, W2s, b2s, smask, alpha, out, valid, chem, chemBf, conv_n);

    if (useBf)
        k_chem_v6<true><<<dim3(CBLK2), dim3(768), 0, stream>>>(
            (const void*)chemBf, edge, W1cT, b1c, W2c, b2c, valid, out);
    else
        k_chem_v6<false><<<dim3(CBLK2), dim3(768), 0, stream>>>(
            (const void*)chem, edge, W1cT, b1c, W2c, b2c, valid, out);
}